// Round 10
// baseline (46.694 us; speedup 1.0000x reference)
//
#include <hip/hip_runtime.h>
#include <hip/hip_bf16.h>

// ws layout (requires ws_size >= 17039360 B):
//   [0, 221184)        : weights as bf16 in 16x16x32 MFMA B-fragment order
//   [221184, 221440)   : 256 B of zeros (OOB halo source)
//   [262144, 17039360) : x_t = x transposed to [b][s][c] bf16 (16 MiB)
#define WS_W_OFF    0
#define WS_ZERO_OFF 221184
#define WS_XT_OFF   262144

typedef __attribute__((ext_vector_type(8))) short s16x8;
typedef __attribute__((ext_vector_type(4))) float f32x4;

#define GLOBAL_AS __attribute__((address_space(1)))
#define LDS_AS    __attribute__((address_space(3)))

__device__ __forceinline__ unsigned short f2bf(float f) {
  unsigned u = __builtin_bit_cast(unsigned, f);
  u = u + 0x7fffu + ((u >> 16) & 1u);
  return (unsigned short)(u >> 16);
}

// ---------------------------------------------------------------------------
// Fused prep (unchanged, verified): blocks [0,432) repack weights;
// blocks [432,4528) transpose x to channels-last bf16.
// Fragment f = (tap*2+h)*4+nf holds B[n][k] for n = nf*16 + (lane&15),
// cin = h*32 + (lane>>4)*8 + j. bf16 index = (f*64 + lane)*8 + j.
__global__ void prep_kernel(const float* __restrict__ x,
                            const float* __restrict__ w,
                            unsigned short* __restrict__ wsw,
                            float* __restrict__ zeros,
                            unsigned short* __restrict__ xt) {
  int blk = blockIdx.x;
  if (blk < 432) {
    int t = blk * 256 + threadIdx.x;             // 110592 threads exactly
    int tap  = t % 27;
    int cin  = (t / 27) & 63;
    int cout = t / (27 * 64);
    int h   = cin >> 5;
    int q   = (cin >> 3) & 3;
    int j   = cin & 7;
    int nf  = cout >> 4;
    int lane = q * 16 + (cout & 15);
    int dst = (((tap * 2 + h) * 4 + nf) * 64 + lane) * 8 + j;
    wsw[dst] = f2bf(w[t]);
    if (t < 64) zeros[t] = 0.0f;
  } else {
    int t  = (blk - 432) * 256 + threadIdx.x;    // 1048576 threads
    int s  = t & 32767;
    int c8 = (t >> 15) & 7;
    int b  = t >> 18;
    const float* src = x + (size_t)(b * 64 + c8 * 8) * 32768 + s;
    s16x8 v;
    #pragma unroll
    for (int k = 0; k < 8; ++k) v[k] = (short)f2bf(src[(size_t)k * 32768]);
    *(s16x8*)(xt + (size_t)(b * 32768 + s) * 64 + c8 * 8) = v;
  }
}

// ---------------------------------------------------------------------------
// Implicit-GEMM conv, cin-SPLIT wave pairs: R8 geometry with the rule-#20
// scratch-spill fixed (reduction is wave-uniform-branched, ALL acc indices
// compile-time; barriers outside the branches).
//
// Block = (b, z-quad, y-quad): 4z x 4y x 32x = 512 outputs x 64 couts,
// 1024 threads = 16 waves, grid 256 = 1 block/CU (153 KB LDS).
// Wave w: tile t_=w>>1 (zi=t_>>1, yi=t_&1 -> z=z0+zi, y-rows y0+2yi,+1),
// h=w&1 = cin half. M_w=64, K_w=32 -> 16 waves/CU = 4 waves/SIMD.
// Per-SIMD matrix demand 33.5K cy = wall; A-LDS (20.7K) and B-L1 (27.6K)
// streams hide under it via 4-way TLP (m114). Tap loop: ZERO barriers.
//
// Halo: pos p (1224 = 6z*6y*34x) at halo[p*128]; 16B cin-chunk c stored at
// slot c ^ (p&7). A-read (lane l: p = p0+(l&15), c = (h*4+(l>>4)) ^ (p&7))
// -> exactly 8 lanes per 16B bank-group = ds_read_b128 floor, conflict-free.
// Staging dest LINEAR (halo + r*16384 + tid*16); swizzle applied to SOURCE
// chunk csrc = (tid&7) ^ ((tid>>3)&7)  (valid since r*128 == 0 mod 8).
__global__ __launch_bounds__(1024, 4) void conv_kernel(const float* __restrict__ bias,
                                                       float* __restrict__ out,
                                                       const char* __restrict__ ws) {
  __shared__ __align__(16) unsigned char halo[1224 * 128];   // 156672 B

  const int tid  = threadIdx.x;
  const int lane = tid & 63;
  const int w    = tid >> 6;                     // wave 0..15
  const int t_   = w >> 1;                       // spatial tile 0..7
  const int h    = w & 1;                        // cin half
  const int zi   = t_ >> 1, yi = t_ & 1;
  // XCD swizzle (256 % 8 == 0 -> bijective): 32 contiguous logical blocks per
  // XCD (fixed b, 4 consecutive z-quads) -> ~3 MB x_t slab mostly L2-resident.
  const int logical = (blockIdx.x & 7) * 32 + (blockIdx.x >> 3);
  const int yq = logical & 7, zq = (logical >> 3) & 7, b = logical >> 6;
  const int z0 = zq * 4, y0 = yq * 4;

  const int r15 = lane & 15;
  const int hi4 = lane >> 4;

  // ---- stage full-K halo: 1224 pos x 128 B, 10 rounds x 128 pos ----
  {
    const int csrc = ((tid & 7) ^ ((tid >> 3) & 7)) * 16;
    #pragma unroll 1
    for (int r = 0; r < 10; ++r) {
      int pos = r * 128 + (tid >> 3);
      if (pos < 1224) {
        int hz = pos / 204; int rem = pos - hz * 204;      // 204 = 6*34
        int hy = rem / 34;  int hx = rem - hy * 34;
        int gz = z0 + hz - 1, gy = y0 + hy - 1, gx = hx - 1;
        bool inb = ((unsigned)gz < 32u) & ((unsigned)gy < 32u) &
                   ((unsigned)gx < 32u);
        int s = (gz * 32 + gy) * 32 + gx;
        int src = inb ? (WS_XT_OFF + (b * 32768 + s) * 128 + csrc)
                      : WS_ZERO_OFF;
        __builtin_amdgcn_global_load_lds(
            (const GLOBAL_AS void*)(ws + src),
            (LDS_AS void*)(&halo[r * 16384 + tid * 16]),
            16, 0, 0);
      }
    }
  }

  const s16x8* __restrict__ wfr = (const s16x8*)(ws + WS_W_OFF);

  f32x4 zero4 = {0.f, 0.f, 0.f, 0.f};
  f32x4 acc[4][4];                               // mf = dy*2+xh ; ALL static
  #pragma unroll
  for (int mf = 0; mf < 4; ++mf)
    #pragma unroll
    for (int nf = 0; nf < 4; ++nf) acc[mf][nf] = zero4;

  // per-lane invariants for the tap loop
  const int pbase = (zi * 6 + yi * 2) * 34 + r15;  // halo pos before tap offs
  const int chunk = h * 4 + hi4;                   // this wave's cin chunk

  __syncthreads();   // drains global_load_lds; halo ready for all waves

  // ---- 27 taps, fully unrolled, zero barriers ----
  #pragma unroll
  for (int tap = 0; tap < 27; ++tap) {
    const int kd = tap / 9, r9 = tap % 9;
    const int kh = r9 / 3, kw = r9 % 3;            // compile-time constants
    s16x8 Bf[4], Af[4];
    #pragma unroll
    for (int nf = 0; nf < 4; ++nf)
      Bf[nf] = wfr[((tap * 2 + h) * 4 + nf) * 64 + lane];
    #pragma unroll
    for (int mf = 0; mf < 4; ++mf) {
      int p = pbase + (kd * 6 + (mf >> 1) + kh) * 34 + kw + (mf & 1) * 16;
      Af[mf] = *(const s16x8*)&halo[p * 128 + ((chunk ^ (p & 7)) << 4)];
    }
    #pragma unroll
    for (int mf = 0; mf < 4; ++mf)
      #pragma unroll
      for (int nf = 0; nf < 4; ++nf)
        acc[mf][nf] = __builtin_amdgcn_mfma_f32_16x16x32_bf16(
            Af[mf], Bf[nf], acc[mf][nf], 0, 0, 0);
  }

  // ---- pairwise K-reduction via LDS (aliased over halo) ----
  // Slot r (= y-row index within the pair) at t_*16384 + r*8192.
  // h=0 gives away row 1 (acc[2..3]), keeps row 0; h=1 gives row 0, keeps 1.
  // Branches are wave-uniform; every index inside is compile-time (rule #20).
  __syncthreads();   // all waves done READING halo
  if (h == 0) {
    const int o = t_ * 16384 + 1 * 8192;
    #pragma unroll
    for (int nf = 0; nf < 4; ++nf) {
      *(f32x4*)&halo[o + (0 * 4 + nf) * 1024 + lane * 16] = acc[2][nf];
      *(f32x4*)&halo[o + (1 * 4 + nf) * 1024 + lane * 16] = acc[3][nf];
    }
  } else {
    const int o = t_ * 16384 + 0 * 8192;
    #pragma unroll
    for (int nf = 0; nf < 4; ++nf) {
      *(f32x4*)&halo[o + (0 * 4 + nf) * 1024 + lane * 16] = acc[0][nf];
      *(f32x4*)&halo[o + (1 * 4 + nf) * 1024 + lane * 16] = acc[1][nf];
    }
  }
  __syncthreads();

  // ---- add partner partials + bias, store own y-row ----
  const int z = z0 + zi;
  const int y = y0 + 2 * yi + h;
  const int ro = t_ * 16384 + h * 8192;          // slot h = the row we keep
  #pragma unroll
  for (int nf = 0; nf < 4; ++nf) {
    int cout = nf * 16 + r15;
    float bv = bias[cout];
    float* orow = out + ((size_t)((b * 64 + cout) * 32 + z) * 32 + y) * 32;
    #pragma unroll
    for (int xh = 0; xh < 2; ++xh) {
      f32x4 part = *(const f32x4*)&halo[ro + (xh * 4 + nf) * 1024 + lane * 16];
      f32x4 v;
      if (h == 0) {
        #pragma unroll
        for (int r = 0; r < 4; ++r) v[r] = acc[0 + xh][nf][r] + part[r] + bv;
      } else {
        #pragma unroll
        for (int r = 0; r < 4; ++r) v[r] = acc[2 + xh][nf][r] + part[r] + bv;
      }
      *(f32x4*)&orow[xh * 16 + hi4 * 4] = v;
    }
  }
}

extern "C" void kernel_launch(void* const* d_in, const int* in_sizes, int n_in,
                              void* d_out, int out_size, void* d_ws, size_t ws_size,
                              hipStream_t stream) {
  const float* x    = (const float*)d_in[0];
  const float* wgt  = (const float*)d_in[1];
  const float* bias = (const float*)d_in[2];
  float* out = (float*)d_out;
  char* ws = (char*)d_ws;

  prep_kernel<<<4528, 256, 0, stream>>>(x, wgt,
                                        (unsigned short*)(ws + WS_W_OFF),
                                        (float*)(ws + WS_ZERO_OFF),
                                        (unsigned short*)(ws + WS_XT_OFF));
  conv_kernel<<<256, 1024, 0, stream>>>(bias, out, ws);
}